// Round 1
// 7739.350 us; speedup vs baseline: 1.0486x; 1.0486x over previous
//
#include <hip/hip_runtime.h>

#define TT 16384
#define BB 8
#define HH 512
#define CC 24
#define KK 100

// ---------------- GEMM: scoresT[b,c,t] = hs[b,t,:] @ W[:,c] + b[c] ----------------
// One thread per row (B*T rows). Output written TRANSPOSED (B,C,T) so the scan
// kernel can bulk-load each channel's score stream with float4 (t-contiguous).
// Stores: 24 scalar stores per thread, coalesced across lanes (consecutive t).
__global__ __launch_bounds__(256) void score_gemm(
    const float* __restrict__ hs, const float* __restrict__ W,
    const float* __restrict__ bias, float* __restrict__ scoresT) {
  const long row = (long)blockIdx.x * 256 + threadIdx.x;
  const int b = (int)(row >> 14);   // TT = 16384 = 2^14
  const int t = (int)(row & (TT - 1));
  const float* x = hs + row * HH;
  float acc[CC];
#pragma unroll
  for (int c = 0; c < CC; ++c) acc[c] = bias[c];
#pragma unroll 2
  for (int h0 = 0; h0 < HH; h0 += 4) {
    float4 xv = *reinterpret_cast<const float4*>(x + h0);
    const float* wp = W + h0 * CC;
#pragma unroll
    for (int c = 0; c < CC; ++c) acc[c] = fmaf(xv.x, wp[c], acc[c]);
#pragma unroll
    for (int c = 0; c < CC; ++c) acc[c] = fmaf(xv.y, wp[CC + c], acc[c]);
#pragma unroll
    for (int c = 0; c < CC; ++c) acc[c] = fmaf(xv.z, wp[2 * CC + c], acc[c]);
#pragma unroll
    for (int c = 0; c < CC; ++c) acc[c] = fmaf(xv.w, wp[3 * CC + c], acc[c]);
  }
  float* op = scoresT + (long)b * CC * TT + t;
#pragma unroll
  for (int c = 0; c < CC; ++c) op[(long)c * TT] = acc[c];
}

// ---------------- DPP 16-lane ops (VALU pipe, no LDS) ----------------
template <int CTRL>
__device__ __forceinline__ float dpp_mov(float x) {
  return __int_as_float(__builtin_amdgcn_update_dpp(
      __float_as_int(x), __float_as_int(x), CTRL, 0xF, 0xF, false));
}
// row_ror:1/2/4/8 -> cyclic butterfly within each aligned 16-lane row; all lanes get total.
__device__ __forceinline__ float bsum16(float x) {
  x += dpp_mov<0x121>(x);
  x += dpp_mov<0x122>(x);
  x += dpp_mov<0x124>(x);
  x += dpp_mov<0x128>(x);
  return x;
}
__device__ __forceinline__ float bmax16(float x) {
  x = fmaxf(x, dpp_mov<0x121>(x));
  x = fmaxf(x, dpp_mov<0x122>(x));
  x = fmaxf(x, dpp_mov<0x124>(x));
  x = fmaxf(x, dpp_mov<0x128>(x));
  return x;
}

// ---------------- Streaming semi-Markov CRF scan ----------------
// One block per batch. 24 groups (one per channel c) x 16 lanes = 384 threads.
// Lane gl of group g holds E[q] = exp(u[t-k] - M) for k = 7*gl + q + 1 (k=1..112,
// weights 0 for k>100). Per step: shift window (rescale folded in), dot with
// exp(dur) weights, DPP butterfly-sum -> alpha; exchange alpha via LDS (1 barrier,
// double-buffered); each group redundantly computes amax / msg[g] with DPP.
// Scores are read from the transposed (B,C,T) buffer as float4 = 4 steps/channel,
// through a 2-deep ring (8-step prefetch distance) so L3/HBM latency is covered.
__global__ __launch_bounds__(384) void crf_scan(
    const float* __restrict__ scoresT, const float* __restrict__ trans,
    const float* __restrict__ db, const int* __restrict__ lengths,
    float* __restrict__ out) {
  const int b = blockIdx.x;
  const int tid = threadIdx.x;
  const int g = tid >> 4;   // channel 0..23
  const int gl = tid & 15;  // lane within group
  __shared__ float alpha_lds[2][32];

  float w[7], E[7];
#pragma unroll
  for (int q = 0; q < 7; ++q) {
    int km1 = 7 * gl + q;  // k-1
    w[q] = (km1 < KK) ? __expf(db[km1 * CC + g]) : 0.0f;
    E[q] = 0.0f;
  }
  float eT1 = __expf(trans[gl * CC + g]);                            // c' = gl
  float eT2 = (gl < 8) ? __expf(trans[(gl + 16) * CC + g]) : 0.0f;  // c' = gl+16
  int len = lengths[b];
  len = len < 1 ? 1 : (len > TT ? TT : len);

  float cum = 0.0f;     // running cum[t][g], redundant across group lanes
  float u_prev = 0.0f;  // u[0] = msg[0] - cum[0] = 0
  float M = -30.0f;     // current scale for E

  const float4* sp4 =
      reinterpret_cast<const float4*>(scoresT + ((long)b * CC + g) * TT);
  float4 buf0 = sp4[0];  // steps 0..3
  float4 buf1 = sp4[1];  // steps 4..7
  const int NJ = TT / 4;

  for (int j = 0; j < NJ; ++j) {
    int jn = j + 2;
    jn = jn < NJ ? jn : NJ - 1;
    float4 nb = sp4[jn];  // prefetch steps 4j+8 .. 4j+11 (in flight across 2 blocks)
    float scs[4] = {buf0.x, buf0.y, buf0.z, buf0.w};
#pragma unroll
    for (int u = 0; u < 4; ++u) {
      const int i = 4 * j + u;  // step t = i+1
      cum += scs[u];

      // scale tracking + fold rescale into the window shift (all inputs available
      // at step start -> schedulable ahead of the LDS exchange)
      float Mn = fmaxf(M - 0.015625f, u_prev - 30.0f);
      float r = __expf(M - Mn);
      float enew = __expf(u_prev - Mn);
      float tmp = dpp_mov<0x111>(E[6]);  // row_shr:1 — E[6] from lane gl-1 (VALU, no LDS)
      M = Mn;
#pragma unroll
      for (int q = 6; q >= 1; --q) E[q] = E[q - 1] * r;
      E[0] = (gl == 0) ? enew : tmp * r;

      // window dot with exp(dur) weights, butterfly-sum over 16 lanes
      float s = E[0] * w[0];
#pragma unroll
      for (int q = 1; q < 7; ++q) s = fmaf(E[q], w[q], s);
      s = bsum16(s);
      float alpha = cum + M + __logf(s);

      if (gl == 0) alpha_lds[i & 1][g] = alpha;
      __syncthreads();

      // msg[g] = amax + log(sum_c' exp(alpha[c'] - amax) * exp(trans[c'][g]))
      float ac1 = alpha_lds[i & 1][gl];
      float ac2 = (gl < 8) ? alpha_lds[i & 1][gl + 16] : -3.0e38f;
      float am = bmax16(fmaxf(ac1, ac2));
      float e1 = __expf(ac1 - am);
      float e2 = __expf(ac2 - am);  // 0 for padded lanes
      float S = bsum16(fmaf(e2, eT2, e1 * eT1));
      float msg = am + __logf(S);
      u_prev = msg - cum;

      if (i == len - 1) {  // partition_b = LSE_c alpha[len][c]; uniform branch
        float se = bsum16(e1 + e2);
        if (tid == 0) out[b] = am + __logf(se);
        return;
      }
    }
    buf0 = buf1;
    buf1 = nb;
  }
}

extern "C" void kernel_launch(void* const* d_in, const int* in_sizes, int n_in,
                              void* d_out, int out_size, void* d_ws, size_t ws_size,
                              hipStream_t stream) {
  const float* hs = (const float*)d_in[0];       // (B,T,H) f32
  const float* W = (const float*)d_in[1];        // (H,C) f32
  const float* bias = (const float*)d_in[2];     // (C,) f32
  const float* trans = (const float*)d_in[3];    // (C,C) f32
  const float* db = (const float*)d_in[4];       // (K,C) f32
  const int* lengths = (const int*)d_in[5];      // (B,) i32
  float* scoresT = (float*)d_ws;                 // (B,C,T) f32 = 12.6 MB scratch

  score_gemm<<<(BB * TT) / 256, 256, 0, stream>>>(hs, W, bias, scoresT);
  crf_scan<<<BB, 384, 0, stream>>>(scoresT, trans, db, lengths, (float*)d_out);
}